// Round 1
// baseline (154.078 us; speedup 1.0000x reference)
//
#include <hip/hip_runtime.h>
#include <hip/hip_bf16.h>

// Problem constants
#define B_  2
#define S_  2048
#define E_  512
#define H_  8
#define D_  64
#define BS_ (B_ * S_)   // 4096 rows
#define N1_ 1536        // fused tri-projection output cols
#define K_  512

typedef __bf16 bf16x8 __attribute__((ext_vector_type(8)));
typedef float  f32x4  __attribute__((ext_vector_type(4)));

// float -> bf16 (RNE) bit trick
__device__ __forceinline__ ushort f2bf(float f) {
    unsigned u = __float_as_uint(f);
    unsigned r = (u + 0x7FFFu + ((u >> 16) & 1u)) >> 16;
    return (ushort)r;
}

// ---------------- conversion kernels ----------------

__global__ void convert_x_kernel(const float* __restrict__ x,
                                 ushort* __restrict__ xb, int n4) {
    int i = blockIdx.x * blockDim.x + threadIdx.x;
    if (i >= n4) return;
    float4 v = ((const float4*)x)[i];
    ushort4 o;
    o.x = f2bf(v.x); o.y = f2bf(v.y); o.z = f2bf(v.z); o.w = f2bf(v.w);
    ((ushort4*)xb)[i] = o;
}

// dst[n*512 + k] = bf16(src[k*512 + n])   (512x512 transpose to N-major)
__global__ void transpose512_kernel(const float* __restrict__ src,
                                    ushort* __restrict__ dst) {
    int tid = blockIdx.x * blockDim.x + threadIdx.x;  // 512*512 threads
    int n = tid >> 9, k = tid & 511;
    dst[tid] = f2bf(src[k * 512 + n]);
    (void)n;
}

__global__ void bias_cat_kernel(const float* __restrict__ bp,
                                const float* __restrict__ bc,
                                const float* __restrict__ bs,
                                float* __restrict__ out) {
    int i = blockIdx.x * blockDim.x + threadIdx.x;  // 1536 threads
    if (i >= 1536) return;
    float v = (i < 512) ? bp[i] : (i < 1024) ? bc[i - 512] : bs[i - 1024];
    out[i] = v;
}

// ---------------- bf16 MFMA GEMM ----------------
// C[M x N] = A[M x K](bf16) * Bt[N x K](bf16)^T + bias[N], fp32 out.
// 64x64 tile per 256-thread block, 4 waves in 2x2, each wave 32x32 via
// 2x2 mfma_f32_16x16x32_bf16 fragments. BK=64, LDS padded +8 bf16.
#define BM 64
#define BN 64
#define BK 64
#define PAD 8

__global__ __launch_bounds__(256) void gemm_bf16_kernel(
    const ushort* __restrict__ A,   // M x K
    const ushort* __restrict__ Bt,  // N x K
    const float*  __restrict__ bias,// N
    float* __restrict__ C,          // M x N
    int N, int K) {
    __shared__ ushort As[BM][BK + PAD];
    __shared__ ushort Bs[BN][BK + PAD];

    const int row0 = blockIdx.y * BM;
    const int col0 = blockIdx.x * BN;
    const int tid  = threadIdx.x;
    const int lane = tid & 63;
    const int wave = tid >> 6;

    f32x4 acc[2][2] = {{{0.f,0.f,0.f,0.f},{0.f,0.f,0.f,0.f}},
                       {{0.f,0.f,0.f,0.f},{0.f,0.f,0.f,0.f}}};

    const int r  = tid >> 3;    // 0..31
    const int cg = tid & 7;     // 0..7 -> 8 bf16 (16B) chunks
    const int wm = wave >> 1, wn = wave & 1;
    const int lrow = lane & 15;
    const int lk   = (lane >> 4) * 8;

    for (int kt = 0; kt < K; kt += BK) {
        #pragma unroll
        for (int half = 0; half < 2; half++) {
            int rr = r + half * 32;
            uint4 av = *(const uint4*)(A  + (size_t)(row0 + rr) * K + kt + cg * 8);
            *(uint4*)(&As[rr][cg * 8]) = av;
            uint4 bv = *(const uint4*)(Bt + (size_t)(col0 + rr) * K + kt + cg * 8);
            *(uint4*)(&Bs[rr][cg * 8]) = bv;
        }
        __syncthreads();

        #pragma unroll
        for (int kk = 0; kk < BK; kk += 32) {
            bf16x8 a0 = *(const bf16x8*)(&As[wm * 32 +      lrow][kk + lk]);
            bf16x8 a1 = *(const bf16x8*)(&As[wm * 32 + 16 + lrow][kk + lk]);
            bf16x8 b0 = *(const bf16x8*)(&Bs[wn * 32 +      lrow][kk + lk]);
            bf16x8 b1 = *(const bf16x8*)(&Bs[wn * 32 + 16 + lrow][kk + lk]);
            acc[0][0] = __builtin_amdgcn_mfma_f32_16x16x32_bf16(a0, b0, acc[0][0], 0, 0, 0);
            acc[0][1] = __builtin_amdgcn_mfma_f32_16x16x32_bf16(a0, b1, acc[0][1], 0, 0, 0);
            acc[1][0] = __builtin_amdgcn_mfma_f32_16x16x32_bf16(a1, b0, acc[1][0], 0, 0, 0);
            acc[1][1] = __builtin_amdgcn_mfma_f32_16x16x32_bf16(a1, b1, acc[1][1], 0, 0, 0);
        }
        __syncthreads();
    }

    // C/D layout: col = lane&15, row = (lane>>4)*4 + reg  [m89/m91 verified]
    const int ccol = lane & 15;
    const int crow = (lane >> 4) * 4;
    #pragma unroll
    for (int im = 0; im < 2; im++) {
        #pragma unroll
        for (int in = 0; in < 2; in++) {
            int gcol = col0 + wn * 32 + in * 16 + ccol;
            float bv = bias[gcol];
            #pragma unroll
            for (int rg = 0; rg < 4; rg++) {
                int grow = row0 + wm * 32 + im * 16 + crow + rg;
                C[(size_t)grow * N + gcol] = acc[im][in][rg] + bv;
            }
        }
    }
}

// ---------------- sparse tree attention over edges ----------------
// PCS row layout per token row w=b*S+i (1536 floats): [p(512) | c(512) | s(512)],
// each 512 = h*64+d. One wave per (b,i); loops all 8 heads.
// Pair set: (i,parent[i]) always; (parent[i],i) unless parent[parent[i]]==i
// (dedup incl. self-loops, matching boolean-mask set semantics).
__global__ __launch_bounds__(256) void tree_attn_kernel(
    const float* __restrict__ PCS, const int* __restrict__ parent,
    float* __restrict__ Z, float* __restrict__ acc) {
    int gtid = blockIdx.x * blockDim.x + threadIdx.x;
    int w    = gtid >> 6;        // 0 .. BS_-1
    int lane = gtid & 63;        // = d
    int b = w >> 11;             // S_ = 2048
    int i = w & (S_ - 1);
    int par = parent[w];
    int rp  = (b << 11) + par;
    bool dup = (parent[rp] == i);

    const float* rowN = PCS + (size_t)w  * N1_;
    const float* rowM = PCS + (size_t)rp * N1_;

    for (int h = 0; h < H_; h++) {
        int o = h * 64 + lane;
        // pair (n=i, m=par)
        float pn = rowN[o];
        float cm = rowM[512 + o];
        float sm = rowM[1024 + o];
        float sc = pn * cm;
        #pragma unroll
        for (int off = 32; off; off >>= 1) sc += __shfl_xor(sc, off);
        float e = expf(sc * 0.125f);               // 1/sqrt(D)=1/8
        atomicAdd(&acc[(size_t)w * E_ + o], e * sm);
        if (lane == 0) atomicAdd(&Z[w * H_ + h], e);

        if (!dup) {
            // pair (n=par, m=i)
            float pm = rowM[o];
            float cn = rowN[512 + o];
            float sn = rowN[1024 + o];
            float sc2 = pm * cn;
            #pragma unroll
            for (int off = 32; off; off >>= 1) sc2 += __shfl_xor(sc2, off);
            float e2 = expf(sc2 * 0.125f);
            atomicAdd(&acc[(size_t)rp * E_ + o], e2 * sn);
            if (lane == 0) atomicAdd(&Z[rp * H_ + h], e2);
        }
    }
}

// attn_bf16[idx] = bf16(acc[idx] / Z[idx>>6]); layouts coincide linearly.
__global__ void normalize_kernel(const float* __restrict__ acc,
                                 const float* __restrict__ Z,
                                 ushort* __restrict__ attn) {
    int i = blockIdx.x * blockDim.x + threadIdx.x;  // BS_*E_ = 2M
    attn[i] = f2bf(acc[i] / Z[i >> 6]);
}

// ---------------- launch ----------------
extern "C" void kernel_launch(void* const* d_in, const int* in_sizes, int n_in,
                              void* d_out, int out_size, void* d_ws, size_t ws_size,
                              hipStream_t stream) {
    const float* x      = (const float*)d_in[0];
    const int*   parent = (const int*)  d_in[1];
    const float* Wp     = (const float*)d_in[2];
    const float* bp     = (const float*)d_in[3];
    const float* Wc     = (const float*)d_in[4];
    const float* bc     = (const float*)d_in[5];
    const float* Ws     = (const float*)d_in[6];
    const float* bs     = (const float*)d_in[7];
    const float* Wo     = (const float*)d_in[8];
    const float* bo     = (const float*)d_in[9];
    float* out = (float*)d_out;

    char* ws = (char*)d_ws;
    // workspace layout (bytes, all 256-aligned)
    ushort* x_bf    = (ushort*)(ws + 0);           //  4,194,304
    ushort* Wcat_t  = (ushort*)(ws + 4194304);     //  1,572,864
    ushort* Wo_t    = (ushort*)(ws + 5767168);     //    524,288
    float*  biascat = (float*) (ws + 6291456);     //      6,144
    float*  PCS     = (float*) (ws + 6299648);     // 25,165,824
    float*  Zd      = (float*) (ws + 31465472);    //    131,072
    float*  accd    = (float*) (ws + 31596544);    //  8,388,608
    ushort* attn_bf = (ushort*)(ws + 39985152);    //  4,194,304  (end ~44.2 MB)

    hipMemsetAsync(Zd,   0, (size_t)BS_ * H_ * sizeof(float), stream);
    hipMemsetAsync(accd, 0, (size_t)BS_ * E_ * sizeof(float), stream);

    convert_x_kernel<<<(BS_ * E_ / 4 + 255) / 256, 256, 0, stream>>>(x, x_bf, BS_ * E_ / 4);
    transpose512_kernel<<<1024, 256, 0, stream>>>(Wp, Wcat_t);
    transpose512_kernel<<<1024, 256, 0, stream>>>(Wc, Wcat_t + 512 * 512);
    transpose512_kernel<<<1024, 256, 0, stream>>>(Ws, Wcat_t + 1024 * 512);
    transpose512_kernel<<<1024, 256, 0, stream>>>(Wo, Wo_t);
    bias_cat_kernel<<<6, 256, 0, stream>>>(bp, bc, bs, biascat);

    // GEMM1: PCS = x @ [Wp|Wc|Ws] + [bp|bc|bs]
    gemm_bf16_kernel<<<dim3(N1_ / BN, BS_ / BM), 256, 0, stream>>>(
        x_bf, Wcat_t, biascat, PCS, N1_, K_);

    // sparse attention
    tree_attn_kernel<<<BS_ * 64 / 256, 256, 0, stream>>>(PCS, parent, Zd, accd);
    normalize_kernel<<<BS_ * E_ / 256, 256, 0, stream>>>(accd, Zd, attn_bf);

    // GEMM2: out = attn @ Wo + bo
    gemm_bf16_kernel<<<dim3(E_ / BN, BS_ / BM), 256, 0, stream>>>(
        attn_bf, Wo_t, bo, out, E_, K_);
}

// Round 2
// 140.975 us; speedup vs baseline: 1.0929x; 1.0929x over previous
//
#include <hip/hip_runtime.h>
#include <hip/hip_bf16.h>

// Problem constants
#define B_  2
#define S_  2048
#define E_  512
#define H_  8
#define D_  64
#define BS_ (B_ * S_)   // 4096 rows
#define N1_ 1536        // fused tri-projection output cols
#define K_  512

typedef __bf16 bf16x8 __attribute__((ext_vector_type(8)));
typedef float  f32x4  __attribute__((ext_vector_type(4)));

// float -> bf16 (RNE) bit trick
__device__ __forceinline__ ushort f2bf(float f) {
    unsigned u = __float_as_uint(f);
    unsigned r = (u + 0x7FFFu + ((u >> 16) & 1u)) >> 16;
    return (ushort)r;
}

// async global->LDS, 16 B per lane; LDS dest = wave-uniform base + lane*16
__device__ __forceinline__ void gld_lds16(const ushort* g, ushort* l) {
    __builtin_amdgcn_global_load_lds(
        (const __attribute__((address_space(1))) unsigned int*)g,
        (__attribute__((address_space(3))) unsigned int*)l, 16, 0, 0);
}

// ---------------- prep kernels ----------------

__global__ void convert_x_kernel(const float* __restrict__ x,
                                 ushort* __restrict__ xb, int n4) {
    int i = blockIdx.x * blockDim.x + threadIdx.x;
    if (i >= n4) return;
    float4 v = ((const float4*)x)[i];
    ushort4 o;
    o.x = f2bf(v.x); o.y = f2bf(v.y); o.z = f2bf(v.z); o.w = f2bf(v.w);
    ((ushort4*)xb)[i] = o;
}

// All four 512x512 weight transposes (K-major -> N-major bf16) in one kernel.
// blockIdx.z selects the matrix; 64x64 tile per block via padded LDS.
__global__ __launch_bounds__(256) void transpose_all_kernel(
    const float* __restrict__ Wp, const float* __restrict__ Wc,
    const float* __restrict__ Ws, const float* __restrict__ Wo,
    ushort* __restrict__ Wcat_t, ushort* __restrict__ Wo_t) {
    __shared__ ushort T[64][65];
    int z = blockIdx.z;
    const float* src = (z == 0) ? Wp : (z == 1) ? Wc : (z == 2) ? Ws : Wo;
    ushort* dst = (z < 3) ? (Wcat_t + (size_t)z * 512 * 512) : Wo_t;
    int n0 = blockIdx.x * 64, k0 = blockIdx.y * 64;
    int tid = threadIdx.x;
    int g = tid >> 6, l = tid & 63;
    #pragma unroll
    for (int r = 0; r < 16; r++) {
        int kk = g * 16 + r;
        T[kk][l] = f2bf(src[(size_t)(k0 + kk) * 512 + n0 + l]);  // coalesced read
    }
    __syncthreads();
    #pragma unroll
    for (int r = 0; r < 16; r++) {
        int nn = g * 16 + r;
        dst[(size_t)(n0 + nn) * 512 + k0 + l] = T[l][nn];        // coalesced write
    }
}

// ---------------- bf16 MFMA GEMM (m97 structure) ----------------
// C[M x N] = A[M x K](bf16) * Bt[N x K](bf16)^T + bias, fp32 out.
// 128 x TN tile per 256-thread block, 4 waves in 2x2; each wave 64 x TN/2
// via 4 x (TN/32) fragments of 16x16x32. BK=64, global_load_lds width 16.
template<int TN>
__global__ __launch_bounds__(256) void gemm_mfma_kernel(
    const ushort* __restrict__ A,   // M x K
    const ushort* __restrict__ Bt,  // N x K
    const float*  __restrict__ b0,  // bias cols [0,512)
    const float*  __restrict__ b1,  // bias cols [512,1024)
    const float*  __restrict__ b2,  // bias cols [1024,1536)
    float* __restrict__ C,          // M x N
    int N, int K) {
    constexpr int TM = 128, TK = 64;
    constexpr int NF = TN / 32;          // n-frags per wave (4 or 2)
    __shared__ ushort As[TM][TK];        // 16 KB, no pad (global_load_lds)
    __shared__ ushort Bs[TN][TK];        // 16 or 8 KB

    const int tid  = threadIdx.x;
    const int lane = tid & 63;
    const int wave = tid >> 6;
    const int wm = wave >> 1, wn = wave & 1;
    const int row0 = blockIdx.y * TM;
    const int col0 = blockIdx.x * TN;

    f32x4 acc[4][NF] = {};

    const int srow = lane >> 3;          // 0..7 row within an 8-row issue
    const int scol = (lane & 7) * 8;     // 8-bf16 chunk

    const int lrow = lane & 15;
    const int lk   = (lane >> 4) * 8;

    for (int kt = 0; kt < K; kt += TK) {
        // A: 4 issues/wave, 8 rows each -> rows wave*32 .. wave*32+31
        const ushort* ga = A + (size_t)(row0 + wave * 32 + srow) * K + kt + scol;
        #pragma unroll
        for (int j = 0; j < 4; j++)
            gld_lds16(ga + (size_t)j * 8 * K, &As[wave * 32 + j * 8][0]);
        // B: NF issues/wave -> rows wave*(TN/4) .. +TN/4-1
        const ushort* gb = Bt + (size_t)(col0 + wave * (TN / 4) + srow) * K + kt + scol;
        #pragma unroll
        for (int j = 0; j < NF; j++)
            gld_lds16(gb + (size_t)j * 8 * K, &Bs[wave * (TN / 4) + j * 8][0]);
        __syncthreads();

        #pragma unroll
        for (int kk = 0; kk < TK; kk += 32) {
            bf16x8 af[4], bf[NF];
            #pragma unroll
            for (int i = 0; i < 4; i++)
                af[i] = *(const bf16x8*)(&As[wm * 64 + i * 16 + lrow][kk + lk]);
            #pragma unroll
            for (int j = 0; j < NF; j++)
                bf[j] = *(const bf16x8*)(&Bs[wn * (TN / 2) + j * 16 + lrow][kk + lk]);
            #pragma unroll
            for (int i = 0; i < 4; i++)
                #pragma unroll
                for (int j = 0; j < NF; j++)
                    acc[i][j] = __builtin_amdgcn_mfma_f32_16x16x32_bf16(
                        af[i], bf[j], acc[i][j], 0, 0, 0);
        }
        __syncthreads();
    }

    // C/D layout: col = lane&15, row = (lane>>4)*4 + reg  [m89/m91 verified]
    const int ccol = lane & 15;
    const int crow = (lane >> 4) * 4;
    #pragma unroll
    for (int j = 0; j < NF; j++) {
        int gcol = col0 + wn * (TN / 2) + j * 16 + ccol;
        float bias = (gcol < 512) ? b0[gcol]
                   : (gcol < 1024) ? b1[gcol - 512] : b2[gcol - 1024];
        #pragma unroll
        for (int i = 0; i < 4; i++) {
            int grow = row0 + wm * 64 + i * 16 + crow;
            #pragma unroll
            for (int rg = 0; rg < 4; rg++)
                C[(size_t)(grow + rg) * N + gcol] = acc[i][j][rg] + bias;
        }
    }
}

// ---------------- sparse tree attention over edges ----------------
// PCS row layout per token row w=b*S+i (1536 floats): [p(512) | c(512) | s(512)],
// each 512 = h*64+d. One wave per (b,i); loops all 8 heads.
// Pair set: (i,parent[i]) always; (parent[i],i) unless parent[parent[i]]==i
// (dedup incl. self-loops, matching boolean-mask set semantics).
__global__ __launch_bounds__(256) void tree_attn_kernel(
    const float* __restrict__ PCS, const int* __restrict__ parent,
    float* __restrict__ Z, float* __restrict__ acc) {
    int gtid = blockIdx.x * blockDim.x + threadIdx.x;
    int w    = gtid >> 6;        // 0 .. BS_-1
    int lane = gtid & 63;        // = d
    int b = w >> 11;             // S_ = 2048
    int i = w & (S_ - 1);
    int par = parent[w];
    int rp  = (b << 11) + par;
    bool dup = (parent[rp] == i);

    const float* rowN = PCS + (size_t)w  * N1_;
    const float* rowM = PCS + (size_t)rp * N1_;

    for (int h = 0; h < H_; h++) {
        int o = h * 64 + lane;
        // pair (n=i, m=par)
        float pn = rowN[o];
        float cm = rowM[512 + o];
        float sm = rowM[1024 + o];
        float sc = pn * cm;
        #pragma unroll
        for (int off = 32; off; off >>= 1) sc += __shfl_xor(sc, off);
        float e = expf(sc * 0.125f);               // 1/sqrt(D)=1/8
        atomicAdd(&acc[(size_t)w * E_ + o], e * sm);
        if (lane == 0) atomicAdd(&Z[w * H_ + h], e);

        if (!dup) {
            // pair (n=par, m=i)
            float pm = rowM[o];
            float cn = rowN[512 + o];
            float sn = rowN[1024 + o];
            float sc2 = pm * cn;
            #pragma unroll
            for (int off = 32; off; off >>= 1) sc2 += __shfl_xor(sc2, off);
            float e2 = expf(sc2 * 0.125f);
            atomicAdd(&acc[(size_t)rp * E_ + o], e2 * sn);
            if (lane == 0) atomicAdd(&Z[rp * H_ + h], e2);
        }
    }
}

// attn_bf16[idx] = bf16(acc[idx] / Z[idx>>6]); layouts coincide linearly.
__global__ void normalize_kernel(const float* __restrict__ acc,
                                 const float* __restrict__ Z,
                                 ushort* __restrict__ attn) {
    int i = blockIdx.x * blockDim.x + threadIdx.x;  // BS_*E_ = 2M
    attn[i] = f2bf(acc[i] / Z[i >> 6]);
}

// ---------------- launch ----------------
extern "C" void kernel_launch(void* const* d_in, const int* in_sizes, int n_in,
                              void* d_out, int out_size, void* d_ws, size_t ws_size,
                              hipStream_t stream) {
    const float* x      = (const float*)d_in[0];
    const int*   parent = (const int*)  d_in[1];
    const float* Wp     = (const float*)d_in[2];
    const float* bp     = (const float*)d_in[3];
    const float* Wc     = (const float*)d_in[4];
    const float* bc     = (const float*)d_in[5];
    const float* Ws     = (const float*)d_in[6];
    const float* bs     = (const float*)d_in[7];
    const float* Wo     = (const float*)d_in[8];
    const float* bo     = (const float*)d_in[9];
    float* out = (float*)d_out;

    char* ws = (char*)d_ws;
    // workspace layout (bytes, 256-aligned)
    ushort* x_bf    = (ushort*)(ws + 0);           //  4,194,304
    ushort* Wcat_t  = (ushort*)(ws + 4194304);     //  1,572,864
    ushort* Wo_t    = (ushort*)(ws + 5767168);     //    524,288
    float*  PCS     = (float*) (ws + 6291456);     // 25,165,824
    float*  Zd      = (float*) (ws + 31457280);    //    131,072
    float*  accd    = (float*) (ws + 31588352);    //  8,388,608
    ushort* attn_bf = (ushort*)(ws + 39976960);    //  4,194,304  (end ~44.2 MB)

    hipMemsetAsync(Zd,   0, (size_t)BS_ * H_ * sizeof(float), stream);
    hipMemsetAsync(accd, 0, (size_t)BS_ * E_ * sizeof(float), stream);

    convert_x_kernel<<<(BS_ * E_ / 4 + 255) / 256, 256, 0, stream>>>(
        x, x_bf, BS_ * E_ / 4);
    transpose_all_kernel<<<dim3(8, 8, 4), 256, 0, stream>>>(
        Wp, Wc, Ws, Wo, Wcat_t, Wo_t);

    // GEMM1: PCS = x @ [Wp|Wc|Ws] + [bp|bc|bs]   (128x128 tiles, 12x32 grid)
    gemm_mfma_kernel<128><<<dim3(N1_ / 128, BS_ / 128), 256, 0, stream>>>(
        x_bf, Wcat_t, bp, bc, bs, PCS, N1_, K_);

    // sparse attention
    tree_attn_kernel<<<BS_ * 64 / 256, 256, 0, stream>>>(PCS, parent, Zd, accd);
    normalize_kernel<<<BS_ * E_ / 256, 256, 0, stream>>>(accd, Zd, attn_bf);

    // GEMM2: out = attn @ Wo + bo   (128x64 tiles, 8x32 grid = 256 blocks)
    gemm_mfma_kernel<64><<<dim3(E_ / 64, BS_ / 128), 256, 0, stream>>>(
        attn_bf, Wo_t, bo, bo, bo, out, E_, K_);
}

// Round 4
// 125.302 us; speedup vs baseline: 1.2297x; 1.1251x over previous
//
#include <hip/hip_runtime.h>
#include <hip/hip_bf16.h>

// Problem constants
#define B_  2
#define S_  2048
#define E_  512
#define H_  8
#define D_  64
#define BS_ (B_ * S_)   // 4096 rows
#define N1_ 1536        // fused tri-projection output cols
#define K_  512

typedef __bf16 bf16x8 __attribute__((ext_vector_type(8)));
typedef float  f32x4  __attribute__((ext_vector_type(4)));

// float -> bf16 (RNE) bit trick
__device__ __forceinline__ ushort f2bf(float f) {
    unsigned u = __float_as_uint(f);
    unsigned r = (u + 0x7FFFu + ((u >> 16) & 1u)) >> 16;
    return (ushort)r;
}
__device__ __forceinline__ float bf2f(ushort b) {
    return __uint_as_float(((unsigned)b) << 16);
}

__device__ __forceinline__ float wave_sum(float v) {
    #pragma unroll
    for (int off = 32; off; off >>= 1) v += __shfl_xor(v, off);
    return v;
}

// async global->LDS, 16 B per lane; LDS dest = wave-uniform base + lane*16
__device__ __forceinline__ void gld_lds16(const ushort* g, ushort* l) {
    __builtin_amdgcn_global_load_lds(
        (const __attribute__((address_space(1))) unsigned int*)g,
        (__attribute__((address_space(3))) unsigned int*)l, 16, 0, 0);
}

// ---------------- prep kernels ----------------

__global__ void convert_x_kernel(const float* __restrict__ x,
                                 ushort* __restrict__ xb, int n4) {
    int i = blockIdx.x * blockDim.x + threadIdx.x;
    if (i >= n4) return;
    float4 v = ((const float4*)x)[i];
    ushort4 o;
    o.x = f2bf(v.x); o.y = f2bf(v.y); o.z = f2bf(v.z); o.w = f2bf(v.w);
    ((ushort4*)xb)[i] = o;
}

// All four 512x512 weight transposes (K-major -> N-major bf16) in one kernel.
__global__ __launch_bounds__(256) void transpose_all_kernel(
    const float* __restrict__ Wp, const float* __restrict__ Wc,
    const float* __restrict__ Ws, const float* __restrict__ Wo,
    ushort* __restrict__ Wcat_t, ushort* __restrict__ Wo_t) {
    __shared__ ushort T[64][65];
    int z = blockIdx.z;
    const float* src = (z == 0) ? Wp : (z == 1) ? Wc : (z == 2) ? Ws : Wo;
    ushort* dst = (z < 3) ? (Wcat_t + (size_t)z * 512 * 512) : Wo_t;
    int n0 = blockIdx.x * 64, k0 = blockIdx.y * 64;
    int tid = threadIdx.x;
    int g = tid >> 6, l = tid & 63;
    #pragma unroll
    for (int r = 0; r < 16; r++) {
        int kk = g * 16 + r;
        T[kk][l] = f2bf(src[(size_t)(k0 + kk) * 512 + n0 + l]);  // coalesced read
    }
    __syncthreads();
    #pragma unroll
    for (int r = 0; r < 16; r++) {
        int nn = g * 16 + r;
        dst[(size_t)(n0 + nn) * 512 + k0 + l] = T[l][nn];        // coalesced write
    }
}

// ---------------- bf16 MFMA GEMM (m97 structure) ----------------
// C[M x N] = A[M x K](bf16) * Bt[N x K](bf16)^T + bias; output fp32 or bf16.
template<int TN, bool BF16OUT>
__global__ __launch_bounds__(256) void gemm_mfma_kernel(
    const ushort* __restrict__ A,   // M x K
    const ushort* __restrict__ Bt,  // N x K
    const float*  __restrict__ b0,  // bias cols [0,512)
    const float*  __restrict__ b1,  // bias cols [512,1024)
    const float*  __restrict__ b2,  // bias cols [1024,1536)
    void* __restrict__ Cv,          // M x N
    int N, int K) {
    constexpr int TM = 128, TK = 64;
    constexpr int NF = TN / 32;          // n-frags per wave (4 or 2)
    __shared__ ushort As[TM][TK];        // 16 KB, no pad (global_load_lds)
    __shared__ ushort Bs[TN][TK];        // 16 or 8 KB

    const int tid  = threadIdx.x;
    const int lane = tid & 63;
    const int wave = tid >> 6;
    const int wm = wave >> 1, wn = wave & 1;
    const int row0 = blockIdx.y * TM;
    const int col0 = blockIdx.x * TN;

    f32x4 acc[4][NF] = {};

    const int srow = lane >> 3;          // 0..7 row within an 8-row issue
    const int scol = (lane & 7) * 8;     // 8-bf16 chunk

    const int lrow = lane & 15;
    const int lk   = (lane >> 4) * 8;

    for (int kt = 0; kt < K; kt += TK) {
        const ushort* ga = A + (size_t)(row0 + wave * 32 + srow) * K + kt + scol;
        #pragma unroll
        for (int j = 0; j < 4; j++)
            gld_lds16(ga + (size_t)j * 8 * K, &As[wave * 32 + j * 8][0]);
        const ushort* gb = Bt + (size_t)(col0 + wave * (TN / 4) + srow) * K + kt + scol;
        #pragma unroll
        for (int j = 0; j < NF; j++)
            gld_lds16(gb + (size_t)j * 8 * K, &Bs[wave * (TN / 4) + j * 8][0]);
        __syncthreads();

        #pragma unroll
        for (int kk = 0; kk < TK; kk += 32) {
            bf16x8 af[4], bfr[NF];
            #pragma unroll
            for (int i = 0; i < 4; i++)
                af[i] = *(const bf16x8*)(&As[wm * 64 + i * 16 + lrow][kk + lk]);
            #pragma unroll
            for (int j = 0; j < NF; j++)
                bfr[j] = *(const bf16x8*)(&Bs[wn * (TN / 2) + j * 16 + lrow][kk + lk]);
            #pragma unroll
            for (int i = 0; i < 4; i++)
                #pragma unroll
                for (int j = 0; j < NF; j++)
                    acc[i][j] = __builtin_amdgcn_mfma_f32_16x16x32_bf16(
                        af[i], bfr[j], acc[i][j], 0, 0, 0);
        }
        __syncthreads();
    }

    // C/D layout: col = lane&15, row = (lane>>4)*4 + reg  [m89/m91 verified]
    const int ccol = lane & 15;
    const int crow = (lane >> 4) * 4;
    #pragma unroll
    for (int j = 0; j < NF; j++) {
        int gcol = col0 + wn * (TN / 2) + j * 16 + ccol;
        float bias = (gcol < 512) ? b0[gcol]
                   : (gcol < 1024) ? b1[gcol - 512] : b2[gcol - 1024];
        #pragma unroll
        for (int i = 0; i < 4; i++) {
            int grow = row0 + wm * 64 + i * 16 + crow;
            #pragma unroll
            for (int rg = 0; rg < 4; rg++) {
                float v = acc[i][j][rg] + bias;
                if (BF16OUT)
                    ((ushort*)Cv)[(size_t)(grow + rg) * N + gcol] = f2bf(v);
                else
                    ((float*)Cv)[(size_t)(grow + rg) * N + gcol] = v;
            }
        }
    }
}

// ---------------- tree attention: deterministic ballot-scan gather ----------------
// PCS (bf16) row layout per token w (1536): [p(512)|c(512)|s(512)], each h*64+d.
// One wave per row n = (b,i). Neighbor set (row of the boolean mask):
//   {parent[n]} ∪ {m : parent[m] == i, same batch} \ duplicates.
// Children found by scanning the batch's parent slice with __ballot; edges
// processed in fixed ascending order -> bit-deterministic. No atomics, no CSR.
__global__ __launch_bounds__(256) void attn_gather_kernel(
    const ushort* __restrict__ PCS, const int* __restrict__ parent,
    ushort* __restrict__ attn) {
    int gtid = blockIdx.x * blockDim.x + threadIdx.x;
    int w    = gtid >> 6;        // token row 0..BS_-1
    int lane = gtid & 63;        // = d
    int bbase = ((w >> 11) << 11);
    int i  = w & (S_ - 1);
    int rp = bbase + parent[w];

    // per-head p fragment of row w (lane holds dim d = lane)
    float pn[H_];
    #pragma unroll
    for (int h = 0; h < H_; h++)
        pn[h] = bf2f(PCS[(size_t)w * N1_ + h * 64 + lane]);

    // parent edge (always present in the mask)
    float Zh[H_], avh[H_];
    {
        const ushort* rm = PCS + (size_t)rp * N1_;
        #pragma unroll
        for (int h = 0; h < H_; h++) {
            float cm = bf2f(rm[512 + h * 64 + lane]);
            float sm = bf2f(rm[1024 + h * 64 + lane]);
            float sc = wave_sum(pn[h] * cm);
            float e = __expf(sc * 0.125f);     // 1/sqrt(D) = 1/8
            Zh[h]  = e;
            avh[h] = e * sm;
        }
    }

    // children: scan this batch's parent slice (2048 ints, 32 per lane)
    for (int t0 = 0; t0 < S_; t0 += 64) {
        int m = bbase + t0 + lane;
        unsigned long long mask = __ballot(parent[m] == i);
        while (mask) {
            int l = __ffsll(mask) - 1;
            mask &= mask - 1;
            int c = bbase + t0 + l;
            if (c == rp) continue;             // mutual/self edge counted once
            const ushort* rc = PCS + (size_t)c * N1_;
            #pragma unroll
            for (int h = 0; h < H_; h++) {
                float cc = bf2f(rc[512 + h * 64 + lane]);
                float sc = wave_sum(pn[h] * cc);
                float e = __expf(sc * 0.125f);
                Zh[h]  += e;
                avh[h] += e * bf2f(rc[1024 + h * 64 + lane]);
            }
        }
    }

    #pragma unroll
    for (int h = 0; h < H_; h++)
        attn[(size_t)w * E_ + h * 64 + lane] = f2bf(avh[h] / Zh[h]);
}

// ---------------- launch ----------------
extern "C" void kernel_launch(void* const* d_in, const int* in_sizes, int n_in,
                              void* d_out, int out_size, void* d_ws, size_t ws_size,
                              hipStream_t stream) {
    const float* x      = (const float*)d_in[0];
    const int*   parent = (const int*)  d_in[1];
    const float* Wp     = (const float*)d_in[2];
    const float* bp     = (const float*)d_in[3];
    const float* Wc     = (const float*)d_in[4];
    const float* bc     = (const float*)d_in[5];
    const float* Ws     = (const float*)d_in[6];
    const float* bs     = (const float*)d_in[7];
    const float* Wo     = (const float*)d_in[8];
    const float* bo     = (const float*)d_in[9];
    float* out = (float*)d_out;

    char* ws = (char*)d_ws;
    // workspace layout (bytes, 256-aligned); every byte read is written first
    ushort* x_bf    = (ushort*)(ws + 0);          //  4,194,304
    ushort* Wcat_t  = (ushort*)(ws + 4194304);    //  1,572,864
    ushort* Wo_t    = (ushort*)(ws + 5767168);    //    524,288
    ushort* PCS_bf  = (ushort*)(ws + 6291456);    // 12,582,912
    ushort* attn_bf = (ushort*)(ws + 18874368);   //  4,194,304  (end ~23.1 MB)

    convert_x_kernel<<<(BS_ * E_ / 4 + 255) / 256, 256, 0, stream>>>(
        x, x_bf, BS_ * E_ / 4);
    transpose_all_kernel<<<dim3(8, 8, 4), 256, 0, stream>>>(
        Wp, Wc, Ws, Wo, Wcat_t, Wo_t);

    // GEMM1: PCS(bf16) = x @ [Wp|Wc|Ws] + [bp|bc|bs]   (128x128 tiles, 12x32)
    gemm_mfma_kernel<128, true><<<dim3(N1_ / 128, BS_ / 128), 256, 0, stream>>>(
        x_bf, Wcat_t, bp, bc, bs, PCS_bf, N1_, K_);

    // tree attention: deterministic gather, no atomics
    attn_gather_kernel<<<BS_ * 64 / 256, 256, 0, stream>>>(
        PCS_bf, parent, attn_bf);

    // GEMM2: out(fp32) = attn @ Wo + bo   (128x64 tiles, 8x32 = 256 blocks)
    gemm_mfma_kernel<64, false><<<dim3(E_ / 64, BS_ / 128), 256, 0, stream>>>(
        attn_bf, Wo_t, bo, bo, bo, out, E_, K_);
}

// Round 5
// 120.087 us; speedup vs baseline: 1.2831x; 1.0434x over previous
//
#include <hip/hip_runtime.h>
#include <hip/hip_bf16.h>

// Problem constants
#define B_  2
#define S_  2048
#define E_  512
#define H_  8
#define D_  64
#define BS_ (B_ * S_)   // 4096 rows
#define N1_ 1536        // fused tri-projection output cols
#define K_  512

typedef __bf16 bf16x8 __attribute__((ext_vector_type(8)));
typedef float  f32x4  __attribute__((ext_vector_type(4)));

// float -> bf16 (RNE) bit trick
__device__ __forceinline__ ushort f2bf(float f) {
    unsigned u = __float_as_uint(f);
    unsigned r = (u + 0x7FFFu + ((u >> 16) & 1u)) >> 16;
    return (ushort)r;
}
__device__ __forceinline__ float bf2f(ushort b) {
    return __uint_as_float(((unsigned)b) << 16);
}

__device__ __forceinline__ float wave_sum(float v) {
    #pragma unroll
    for (int off = 32; off; off >>= 1) v += __shfl_xor(v, off);
    return v;
}

// async global->LDS, 16 B per lane; LDS dest = wave-uniform base + lane*16
__device__ __forceinline__ void gld_lds16(const ushort* g, ushort* l) {
    __builtin_amdgcn_global_load_lds(
        (const __attribute__((address_space(1))) unsigned int*)g,
        (__attribute__((address_space(3))) unsigned int*)l, 16, 0, 0);
}

// ---------------- merged prep kernel ----------------
// blocks [0,2048): fp32->bf16 convert of x (one float4 per thread)
// blocks [2048,2304): 64x64 transpose tiles of the four 512x512 weights
__global__ __launch_bounds__(256) void prep_kernel(
    const float* __restrict__ x, ushort* __restrict__ xb,
    const float* __restrict__ Wp, const float* __restrict__ Wc,
    const float* __restrict__ Ws, const float* __restrict__ Wo,
    ushort* __restrict__ Wcat_t, ushort* __restrict__ Wo_t) {
    int bid = blockIdx.x;
    int tid = threadIdx.x;
    if (bid < 2048) {
        int i = bid * 256 + tid;          // 524288 float4s total
        float4 v = ((const float4*)x)[i];
        ushort4 o;
        o.x = f2bf(v.x); o.y = f2bf(v.y); o.z = f2bf(v.z); o.w = f2bf(v.w);
        ((ushort4*)xb)[i] = o;
        return;
    }
    __shared__ ushort T[64][65];
    int bid2 = bid - 2048;                // 0..255
    int z = bid2 >> 6;
    int t = bid2 & 63;
    const float* src = (z == 0) ? Wp : (z == 1) ? Wc : (z == 2) ? Ws : Wo;
    ushort* dst = (z < 3) ? (Wcat_t + (size_t)z * 512 * 512) : Wo_t;
    int n0 = (t & 7) * 64, k0 = (t >> 3) * 64;
    int g = tid >> 6, l = tid & 63;
    #pragma unroll
    for (int r = 0; r < 16; r++) {
        int kk = g * 16 + r;
        T[kk][l] = f2bf(src[(size_t)(k0 + kk) * 512 + n0 + l]);  // coalesced read
    }
    __syncthreads();
    #pragma unroll
    for (int r = 0; r < 16; r++) {
        int nn = g * 16 + r;
        dst[(size_t)(n0 + nn) * 512 + k0 + l] = T[l][nn];        // coalesced write
    }
}

// ---------------- bf16 MFMA GEMM (m97 structure) ----------------
// C[M x N] = A[M x K](bf16) * Bt[N x K](bf16)^T + bias; output fp32 or bf16.
// TM=128 rows, TN columns per 256-thread block; TN=64 -> 24 KB LDS, NF=2.
template<int TN, bool BF16OUT>
__global__ __launch_bounds__(256) void gemm_mfma_kernel(
    const ushort* __restrict__ A,   // M x K
    const ushort* __restrict__ Bt,  // N x K
    const float*  __restrict__ b0,  // bias cols [0,512)
    const float*  __restrict__ b1,  // bias cols [512,1024)
    const float*  __restrict__ b2,  // bias cols [1024,1536)
    void* __restrict__ Cv,          // M x N
    int N, int K) {
    constexpr int TM = 128, TK = 64;
    constexpr int NF = TN / 32;          // n-frags per wave
    __shared__ ushort As[TM][TK];        // 16 KB, no pad (global_load_lds)
    __shared__ ushort Bs[TN][TK];

    const int tid  = threadIdx.x;
    const int lane = tid & 63;
    const int wave = tid >> 6;
    const int wm = wave >> 1, wn = wave & 1;
    const int row0 = blockIdx.y * TM;
    const int col0 = blockIdx.x * TN;

    f32x4 acc[4][NF] = {};

    const int srow = lane >> 3;          // 0..7 row within an 8-row issue
    const int scol = (lane & 7) * 8;     // 8-bf16 chunk

    const int lrow = lane & 15;
    const int lk   = (lane >> 4) * 8;

    for (int kt = 0; kt < K; kt += TK) {
        const ushort* ga = A + (size_t)(row0 + wave * 32 + srow) * K + kt + scol;
        #pragma unroll
        for (int j = 0; j < 4; j++)
            gld_lds16(ga + (size_t)j * 8 * K, &As[wave * 32 + j * 8][0]);
        const ushort* gb = Bt + (size_t)(col0 + wave * (TN / 4) + srow) * K + kt + scol;
        #pragma unroll
        for (int j = 0; j < NF; j++)
            gld_lds16(gb + (size_t)j * 8 * K, &Bs[wave * (TN / 4) + j * 8][0]);
        __syncthreads();

        #pragma unroll
        for (int kk = 0; kk < TK; kk += 32) {
            bf16x8 af[4], bfr[NF];
            #pragma unroll
            for (int i = 0; i < 4; i++)
                af[i] = *(const bf16x8*)(&As[wm * 64 + i * 16 + lrow][kk + lk]);
            #pragma unroll
            for (int j = 0; j < NF; j++)
                bfr[j] = *(const bf16x8*)(&Bs[wn * (TN / 2) + j * 16 + lrow][kk + lk]);
            #pragma unroll
            for (int i = 0; i < 4; i++)
                #pragma unroll
                for (int j = 0; j < NF; j++)
                    acc[i][j] = __builtin_amdgcn_mfma_f32_16x16x32_bf16(
                        af[i], bfr[j], acc[i][j], 0, 0, 0);
        }
        __syncthreads();
    }

    // C/D layout: col = lane&15, row = (lane>>4)*4 + reg  [m89/m91 verified]
    const int ccol = lane & 15;
    const int crow = (lane >> 4) * 4;
    #pragma unroll
    for (int j = 0; j < NF; j++) {
        int gcol = col0 + wn * (TN / 2) + j * 16 + ccol;
        float bias = (gcol < 512) ? b0[gcol]
                   : (gcol < 1024) ? b1[gcol - 512] : b2[gcol - 1024];
        #pragma unroll
        for (int i = 0; i < 4; i++) {
            int grow = row0 + wm * 64 + i * 16 + crow;
            #pragma unroll
            for (int rg = 0; rg < 4; rg++) {
                float v = acc[i][j][rg] + bias;
                if (BF16OUT)
                    ((ushort*)Cv)[(size_t)(grow + rg) * N + gcol] = f2bf(v);
                else
                    ((float*)Cv)[(size_t)(grow + rg) * N + gcol] = v;
            }
        }
    }
}

// ---------------- tree attention: deterministic ballot-scan gather ----------------
// PCS (bf16) row layout per token w (1536): [p(512)|c(512)|s(512)], each h*64+d.
// One wave per row n = (b,i). Neighbor set: {parent[n]} ∪ {m : parent[m]==i}
// minus duplicates. Children found by int4-scanning the batch's parent slice
// with __ballot; fixed processing order -> bit-deterministic. No atomics.
__global__ __launch_bounds__(256) void attn_gather_kernel(
    const ushort* __restrict__ PCS, const int* __restrict__ parent,
    ushort* __restrict__ attn) {
    int gtid = blockIdx.x * blockDim.x + threadIdx.x;
    int w    = gtid >> 6;        // token row 0..BS_-1
    int lane = gtid & 63;        // = d
    int bbase = ((w >> 11) << 11);
    int i  = w & (S_ - 1);
    int rp = bbase + parent[w];

    // per-head p fragment of row w (lane holds dim d = lane)
    float pn[H_];
    #pragma unroll
    for (int h = 0; h < H_; h++)
        pn[h] = bf2f(PCS[(size_t)w * N1_ + h * 64 + lane]);

    // parent edge (always present in the mask)
    float Zh[H_], avh[H_];
    {
        const ushort* rm = PCS + (size_t)rp * N1_;
        #pragma unroll
        for (int h = 0; h < H_; h++) {
            float cm = bf2f(rm[512 + h * 64 + lane]);
            float sm = bf2f(rm[1024 + h * 64 + lane]);
            float sc = wave_sum(pn[h] * cm);
            float e = __expf(sc * 0.125f);     // 1/sqrt(D) = 1/8
            Zh[h]  = e;
            avh[h] = e * sm;
        }
    }

    // children: scan this batch's parent slice, 256 ints per step (int4/lane)
    for (int t0 = 0; t0 < S_; t0 += 256) {
        int4 pv = *(const int4*)(parent + bbase + t0 + lane * 4);
        int pc[4] = {pv.x, pv.y, pv.z, pv.w};
        #pragma unroll
        for (int jj = 0; jj < 4; jj++) {
            unsigned long long mask = __ballot(pc[jj] == i);
            while (mask) {
                int l = __ffsll(mask) - 1;
                mask &= mask - 1;
                int c = bbase + t0 + l * 4 + jj;
                if (c == rp) continue;         // mutual/self edge counted once
                const ushort* rc = PCS + (size_t)c * N1_;
                #pragma unroll
                for (int h = 0; h < H_; h++) {
                    float cc = bf2f(rc[512 + h * 64 + lane]);
                    float sc = wave_sum(pn[h] * cc);
                    float e = __expf(sc * 0.125f);
                    Zh[h]  += e;
                    avh[h] += e * bf2f(rc[1024 + h * 64 + lane]);
                }
            }
        }
    }

    #pragma unroll
    for (int h = 0; h < H_; h++)
        attn[(size_t)w * E_ + h * 64 + lane] = f2bf(avh[h] / Zh[h]);
}

// ---------------- launch ----------------
extern "C" void kernel_launch(void* const* d_in, const int* in_sizes, int n_in,
                              void* d_out, int out_size, void* d_ws, size_t ws_size,
                              hipStream_t stream) {
    const float* x      = (const float*)d_in[0];
    const int*   parent = (const int*)  d_in[1];
    const float* Wp     = (const float*)d_in[2];
    const float* bp     = (const float*)d_in[3];
    const float* Wc     = (const float*)d_in[4];
    const float* bc     = (const float*)d_in[5];
    const float* Ws     = (const float*)d_in[6];
    const float* bs     = (const float*)d_in[7];
    const float* Wo     = (const float*)d_in[8];
    const float* bo     = (const float*)d_in[9];
    float* out = (float*)d_out;

    char* ws = (char*)d_ws;
    // workspace layout (bytes, 256-aligned); every byte read is written first
    ushort* x_bf    = (ushort*)(ws + 0);          //  4,194,304
    ushort* Wcat_t  = (ushort*)(ws + 4194304);    //  1,572,864
    ushort* Wo_t    = (ushort*)(ws + 5767168);    //    524,288
    ushort* PCS_bf  = (ushort*)(ws + 6291456);    // 12,582,912
    ushort* attn_bf = (ushort*)(ws + 18874368);   //  4,194,304  (end ~23.1 MB)

    // prep: convert x (2048 blocks) + transpose weights (256 blocks)
    prep_kernel<<<2304, 256, 0, stream>>>(x, x_bf, Wp, Wc, Ws, Wo, Wcat_t, Wo_t);

    // GEMM1: PCS(bf16) = x @ [Wp|Wc|Ws] + [bp|bc|bs]
    // TN=64 -> 24x32 = 768 blocks = 3.0 blocks/CU (balanced; 128-tile was 1.5)
    gemm_mfma_kernel<64, true><<<dim3(N1_ / 64, BS_ / 128), 256, 0, stream>>>(
        x_bf, Wcat_t, bp, bc, bs, PCS_bf, N1_, K_);

    // tree attention: deterministic gather, no atomics
    attn_gather_kernel<<<BS_ * 64 / 256, 256, 0, stream>>>(
        PCS_bf, parent, attn_bf);

    // GEMM2: out(fp32) = attn @ Wo + bo   (8x32 = 256 blocks)
    gemm_mfma_kernel<64, false><<<dim3(E_ / 64, BS_ / 128), 256, 0, stream>>>(
        attn_bf, Wo_t, bo, bo, bo, out, E_, K_);
}

// Round 6
// 116.432 us; speedup vs baseline: 1.3233x; 1.0314x over previous
//
#include <hip/hip_runtime.h>
#include <hip/hip_bf16.h>

// Problem constants
#define B_  2
#define S_  2048
#define E_  512
#define H_  8
#define D_  64
#define BS_ (B_ * S_)   // 4096 rows
#define N1_ 1536        // fused tri-projection output cols
#define K_  512

typedef __bf16 bf16x8 __attribute__((ext_vector_type(8)));
typedef float  f32x4  __attribute__((ext_vector_type(4)));
typedef unsigned short us8 __attribute__((ext_vector_type(8)));

// float -> bf16 (RNE) bit trick
__device__ __forceinline__ ushort f2bf(float f) {
    unsigned u = __float_as_uint(f);
    unsigned r = (u + 0x7FFFu + ((u >> 16) & 1u)) >> 16;
    return (ushort)r;
}
__device__ __forceinline__ float bf2f(ushort b) {
    return __uint_as_float(((unsigned)b) << 16);
}

// async global->LDS, 16 B per lane; LDS dest = wave-uniform base + lane*size
__device__ __forceinline__ void gld_lds16(const ushort* g, ushort* l) {
    __builtin_amdgcn_global_load_lds(
        (const __attribute__((address_space(1))) unsigned int*)g,
        (__attribute__((address_space(3))) unsigned int*)l, 16, 0, 0);
}

// ---------------- merged prep kernel ----------------
// blocks [0,2048): fp32->bf16 convert of x (one float4 per thread)
// blocks [2048,2304): 64x64 transpose tiles of the four 512x512 weights
__global__ __launch_bounds__(256) void prep_kernel(
    const float* __restrict__ x, ushort* __restrict__ xb,
    const float* __restrict__ Wp, const float* __restrict__ Wc,
    const float* __restrict__ Ws, const float* __restrict__ Wo,
    ushort* __restrict__ Wcat_t, ushort* __restrict__ Wo_t) {
    int bid = blockIdx.x;
    int tid = threadIdx.x;
    if (bid < 2048) {
        int i = bid * 256 + tid;          // 524288 float4s total
        float4 v = ((const float4*)x)[i];
        ushort4 o;
        o.x = f2bf(v.x); o.y = f2bf(v.y); o.z = f2bf(v.z); o.w = f2bf(v.w);
        ((ushort4*)xb)[i] = o;
        return;
    }
    __shared__ ushort T[64][65];
    int bid2 = bid - 2048;                // 0..255
    int z = bid2 >> 6;
    int t = bid2 & 63;
    const float* src = (z == 0) ? Wp : (z == 1) ? Wc : (z == 2) ? Ws : Wo;
    ushort* dst = (z < 3) ? (Wcat_t + (size_t)z * 512 * 512) : Wo_t;
    int n0 = (t & 7) * 64, k0 = (t >> 3) * 64;
    int g = tid >> 6, l = tid & 63;
    #pragma unroll
    for (int r = 0; r < 16; r++) {
        int kk = g * 16 + r;
        T[kk][l] = f2bf(src[(size_t)(k0 + kk) * 512 + n0 + l]);  // coalesced read
    }
    __syncthreads();
    #pragma unroll
    for (int r = 0; r < 16; r++) {
        int nn = g * 16 + r;
        dst[(size_t)(n0 + nn) * 512 + k0 + l] = T[l][nn];        // coalesced write
    }
}

// ---------------- bf16 MFMA GEMM (m97 structure) ----------------
// C[M x N] = A[M x K](bf16) * Bt[N x K](bf16)^T + bias; output fp32 or bf16.
// TM=128 rows, TN columns per 256-thread block; TN=64 -> 24 KB LDS, NF=2.
template<int TN, bool BF16OUT>
__global__ __launch_bounds__(256) void gemm_mfma_kernel(
    const ushort* __restrict__ A,   // M x K
    const ushort* __restrict__ Bt,  // N x K
    const float*  __restrict__ b0,  // bias cols [0,512)
    const float*  __restrict__ b1,  // bias cols [512,1024)
    const float*  __restrict__ b2,  // bias cols [1024,1536)
    void* __restrict__ Cv,          // M x N
    int N, int K) {
    constexpr int TM = 128, TK = 64;
    constexpr int NF = TN / 32;          // n-frags per wave
    __shared__ ushort As[TM][TK];        // 16 KB, no pad (global_load_lds)
    __shared__ ushort Bs[TN][TK];

    const int tid  = threadIdx.x;
    const int lane = tid & 63;
    const int wave = tid >> 6;
    const int wm = wave >> 1, wn = wave & 1;
    const int row0 = blockIdx.y * TM;
    const int col0 = blockIdx.x * TN;

    f32x4 acc[4][NF] = {};

    const int srow = lane >> 3;          // 0..7 row within an 8-row issue
    const int scol = (lane & 7) * 8;     // 8-bf16 chunk

    const int lrow = lane & 15;
    const int lk   = (lane >> 4) * 8;

    for (int kt = 0; kt < K; kt += TK) {
        const ushort* ga = A + (size_t)(row0 + wave * 32 + srow) * K + kt + scol;
        #pragma unroll
        for (int j = 0; j < 4; j++)
            gld_lds16(ga + (size_t)j * 8 * K, &As[wave * 32 + j * 8][0]);
        const ushort* gb = Bt + (size_t)(col0 + wave * (TN / 4) + srow) * K + kt + scol;
        #pragma unroll
        for (int j = 0; j < NF; j++)
            gld_lds16(gb + (size_t)j * 8 * K, &Bs[wave * (TN / 4) + j * 8][0]);
        __syncthreads();

        #pragma unroll
        for (int kk = 0; kk < TK; kk += 32) {
            bf16x8 af[4], bfr[NF];
            #pragma unroll
            for (int i = 0; i < 4; i++)
                af[i] = *(const bf16x8*)(&As[wm * 64 + i * 16 + lrow][kk + lk]);
            #pragma unroll
            for (int j = 0; j < NF; j++)
                bfr[j] = *(const bf16x8*)(&Bs[wn * (TN / 2) + j * 16 + lrow][kk + lk]);
            #pragma unroll
            for (int i = 0; i < 4; i++)
                #pragma unroll
                for (int j = 0; j < NF; j++)
                    acc[i][j] = __builtin_amdgcn_mfma_f32_16x16x32_bf16(
                        af[i], bfr[j], acc[i][j], 0, 0, 0);
        }
        __syncthreads();
    }

    // C/D layout: col = lane&15, row = (lane>>4)*4 + reg  [m89/m91 verified]
    const int ccol = lane & 15;
    const int crow = (lane >> 4) * 4;
    #pragma unroll
    for (int j = 0; j < NF; j++) {
        int gcol = col0 + wn * (TN / 2) + j * 16 + ccol;
        float bias = (gcol < 512) ? b0[gcol]
                   : (gcol < 1024) ? b1[gcol - 512] : b2[gcol - 1024];
        #pragma unroll
        for (int i = 0; i < 4; i++) {
            int grow = row0 + wm * 64 + i * 16 + crow;
            #pragma unroll
            for (int rg = 0; rg < 4; rg++) {
                float v = acc[i][j][rg] + bias;
                if (BF16OUT)
                    ((ushort*)Cv)[(size_t)(grow + rg) * N + gcol] = f2bf(v);
                else
                    ((float*)Cv)[(size_t)(grow + rg) * N + gcol] = v;
            }
        }
    }
}

// ---------------- tree attention: 16B/lane ballot-scan gather ----------------
// PCS (bf16) row layout per token w (1536): [p(512)|c(512)|s(512)], each h*64+d.
// One wave per row n. Lane L owns 8 consecutive elements at offset L*8 of each
// 512-segment: head h = L>>3, dims (L&7)*8..+7. Per edge: two dwordx4 loads
// (c,s segments), 8-FMA dot partial, shfl_xor(1,2,4) reduce within the 8-lane
// head group, one exp, 8 FMAs. Neighbor set {parent[n]} ∪ {m:parent[m]==n}
// minus duplicates, processed in fixed order -> bit-deterministic. No atomics.
__global__ __launch_bounds__(256) void attn_gather_kernel(
    const ushort* __restrict__ PCS, const int* __restrict__ parent,
    ushort* __restrict__ attn) {
    int gtid = blockIdx.x * blockDim.x + threadIdx.x;
    int w    = gtid >> 6;        // token row 0..BS_-1
    int lane = gtid & 63;
    int bbase = ((w >> 11) << 11);
    int i  = w & (S_ - 1);
    int rp = bbase + parent[w];

    // p fragment: 8 consecutive bf16 at w*1536 + lane*8
    float pnf[8];
    {
        us8 p8 = *(const us8*)(PCS + (size_t)w * N1_ + lane * 8);
        #pragma unroll
        for (int j = 0; j < 8; j++) pnf[j] = bf2f(p8[j]);
    }

    float Z, av[8];
    // parent edge (always present in the mask)
    {
        const ushort* rm = PCS + (size_t)rp * N1_;
        us8 c8 = *(const us8*)(rm + 512  + lane * 8);
        us8 s8 = *(const us8*)(rm + 1024 + lane * 8);
        float t = 0.f;
        #pragma unroll
        for (int j = 0; j < 8; j++) t += pnf[j] * bf2f(c8[j]);
        t += __shfl_xor(t, 1); t += __shfl_xor(t, 2); t += __shfl_xor(t, 4);
        float e = __expf(t * 0.125f);          // 1/sqrt(D) = 1/8
        Z = e;
        #pragma unroll
        for (int j = 0; j < 8; j++) av[j] = e * bf2f(s8[j]);
    }

    // children: scan this batch's parent slice, 256 ints per step (int4/lane)
    for (int t0 = 0; t0 < S_; t0 += 256) {
        int4 pv = *(const int4*)(parent + bbase + t0 + lane * 4);
        int pc[4] = {pv.x, pv.y, pv.z, pv.w};
        #pragma unroll
        for (int jj = 0; jj < 4; jj++) {
            unsigned long long mask = __ballot(pc[jj] == i);
            while (mask) {
                int l = __ffsll(mask) - 1;
                mask &= mask - 1;
                int c = bbase + t0 + l * 4 + jj;
                if (c == rp) continue;         // mutual/self edge counted once
                const ushort* rc = PCS + (size_t)c * N1_;
                us8 c8 = *(const us8*)(rc + 512  + lane * 8);
                us8 s8 = *(const us8*)(rc + 1024 + lane * 8);
                float t = 0.f;
                #pragma unroll
                for (int j = 0; j < 8; j++) t += pnf[j] * bf2f(c8[j]);
                t += __shfl_xor(t, 1); t += __shfl_xor(t, 2); t += __shfl_xor(t, 4);
                float e = __expf(t * 0.125f);
                Z += e;
                #pragma unroll
                for (int j = 0; j < 8; j++) av[j] += e * bf2f(s8[j]);
            }
        }
    }

    float rz = 1.0f / Z;
    us8 o8;
    #pragma unroll
    for (int j = 0; j < 8; j++) o8[j] = f2bf(av[j] * rz);
    *(us8*)(attn + (size_t)w * E_ + lane * 8) = o8;
}

// ---------------- launch ----------------
extern "C" void kernel_launch(void* const* d_in, const int* in_sizes, int n_in,
                              void* d_out, int out_size, void* d_ws, size_t ws_size,
                              hipStream_t stream) {
    const float* x      = (const float*)d_in[0];
    const int*   parent = (const int*)  d_in[1];
    const float* Wp     = (const float*)d_in[2];
    const float* bp     = (const float*)d_in[3];
    const float* Wc     = (const float*)d_in[4];
    const float* bc     = (const float*)d_in[5];
    const float* Ws     = (const float*)d_in[6];
    const float* bs     = (const float*)d_in[7];
    const float* Wo     = (const float*)d_in[8];
    const float* bo     = (const float*)d_in[9];
    float* out = (float*)d_out;

    char* ws = (char*)d_ws;
    // workspace layout (bytes, 256-aligned); every byte read is written first
    ushort* x_bf    = (ushort*)(ws + 0);          //  4,194,304
    ushort* Wcat_t  = (ushort*)(ws + 4194304);    //  1,572,864
    ushort* Wo_t    = (ushort*)(ws + 5767168);    //    524,288
    ushort* PCS_bf  = (ushort*)(ws + 6291456);    // 12,582,912
    ushort* attn_bf = (ushort*)(ws + 18874368);   //  4,194,304  (end ~23.1 MB)

    // prep: convert x (2048 blocks) + transpose weights (256 blocks)
    prep_kernel<<<2304, 256, 0, stream>>>(x, x_bf, Wp, Wc, Ws, Wo, Wcat_t, Wo_t);

    // GEMM1: PCS(bf16) = x @ [Wp|Wc|Ws] + [bp|bc|bs]   (24x32 = 768 blocks)
    gemm_mfma_kernel<64, true><<<dim3(N1_ / 64, BS_ / 128), 256, 0, stream>>>(
        x_bf, Wcat_t, bp, bc, bs, PCS_bf, N1_, K_);

    // tree attention: deterministic gather, 16B/lane loads, no atomics
    attn_gather_kernel<<<BS_ * 64 / 256, 256, 0, stream>>>(
        PCS_bf, parent, attn_bf);

    // GEMM2: out(fp32) = attn @ Wo + bo   (8x32 = 256 blocks)
    gemm_mfma_kernel<64, false><<<dim3(E_ / 64, BS_ / 128), 256, 0, stream>>>(
        attn_bf, Wo_t, bo, bo, bo, out, E_, K_);
}

// Round 8
// 114.712 us; speedup vs baseline: 1.3432x; 1.0150x over previous
//
#include <hip/hip_runtime.h>
#include <hip/hip_bf16.h>

// Problem constants
#define B_  2
#define S_  2048
#define E_  512
#define H_  8
#define D_  64
#define BS_ (B_ * S_)   // 4096 rows
#define N1_ 1536        // fused tri-projection output cols
#define K_  512

typedef __bf16 bf16x8 __attribute__((ext_vector_type(8)));
typedef float  f32x4  __attribute__((ext_vector_type(4)));
typedef unsigned short us8 __attribute__((ext_vector_type(8)));

// float -> bf16 (RNE) bit trick
__device__ __forceinline__ ushort f2bf(float f) {
    unsigned u = __float_as_uint(f);
    unsigned r = (u + 0x7FFFu + ((u >> 16) & 1u)) >> 16;
    return (ushort)r;
}
__device__ __forceinline__ float bf2f(ushort b) {
    return __uint_as_float(((unsigned)b) << 16);
}

// async global->LDS, 16 B per lane; LDS dest = wave-uniform base + lane*size
__device__ __forceinline__ void gld_lds16(const ushort* g, ushort* l) {
    __builtin_amdgcn_global_load_lds(
        (const __attribute__((address_space(1))) unsigned int*)g,
        (__attribute__((address_space(3))) unsigned int*)l, 16, 0, 0);
}

// ---------------- merged prep kernel ----------------
// blocks [0,2048): fp32->bf16 convert of x (one float4 per thread)
// blocks [2048,2304): 64x64 transpose tiles of the four 512x512 weights
__global__ __launch_bounds__(256) void prep_kernel(
    const float* __restrict__ x, ushort* __restrict__ xb,
    const float* __restrict__ Wp, const float* __restrict__ Wc,
    const float* __restrict__ Ws, const float* __restrict__ Wo,
    ushort* __restrict__ Wcat_t, ushort* __restrict__ Wo_t) {
    int bid = blockIdx.x;
    int tid = threadIdx.x;
    if (bid < 2048) {
        int i = bid * 256 + tid;          // 524288 float4s total
        float4 v = ((const float4*)x)[i];
        ushort4 o;
        o.x = f2bf(v.x); o.y = f2bf(v.y); o.z = f2bf(v.z); o.w = f2bf(v.w);
        ((ushort4*)xb)[i] = o;
        return;
    }
    __shared__ ushort T[64][65];
    int bid2 = bid - 2048;                // 0..255
    int z = bid2 >> 6;
    int t = bid2 & 63;
    const float* src = (z == 0) ? Wp : (z == 1) ? Wc : (z == 2) ? Ws : Wo;
    ushort* dst = (z < 3) ? (Wcat_t + (size_t)z * 512 * 512) : Wo_t;
    int n0 = (t & 7) * 64, k0 = (t >> 3) * 64;
    int g = tid >> 6, l = tid & 63;
    #pragma unroll
    for (int r = 0; r < 16; r++) {
        int kk = g * 16 + r;
        T[kk][l] = f2bf(src[(size_t)(k0 + kk) * 512 + n0 + l]);  // coalesced read
    }
    __syncthreads();
    #pragma unroll
    for (int r = 0; r < 16; r++) {
        int nn = g * 16 + r;
        dst[(size_t)(n0 + nn) * 512 + k0 + l] = T[l][nn];        // coalesced write
    }
}

// ---------------- bf16 MFMA GEMM (m97 structure, tile-templated) ----------------
// C[M x N] = A[M x K](bf16) * Bt[N x K](bf16)^T + bias; output fp32 or bf16.
// 256 threads = 4 waves in 2x2; per-wave FM x NF fragments of 16x16x32.
template<int TM, int TN, bool BF16OUT>
__global__ __launch_bounds__(256) void gemm_mfma_kernel(
    const ushort* __restrict__ A,   // M x K
    const ushort* __restrict__ Bt,  // N x K
    const float*  __restrict__ b0,  // bias cols [0,512)
    const float*  __restrict__ b1,  // bias cols [512,1024)
    const float*  __restrict__ b2,  // bias cols [1024,1536)
    void* __restrict__ Cv,          // M x N
    int N, int K) {
    constexpr int TK = 64;
    constexpr int FM = TM / 32;          // m-frags per wave
    constexpr int NF = TN / 32;          // n-frags per wave
    __shared__ ushort As[TM][TK];        // no pad (global_load_lds layout)
    __shared__ ushort Bs[TN][TK];

    const int tid  = threadIdx.x;
    const int lane = tid & 63;
    const int wave = tid >> 6;
    const int wm = wave >> 1, wn = wave & 1;
    const int row0 = blockIdx.y * TM;
    const int col0 = blockIdx.x * TN;

    f32x4 acc[FM][NF] = {};

    const int srow = lane >> 3;          // 0..7 row within an 8-row issue
    const int scol = (lane & 7) * 8;     // 8-bf16 chunk

    const int lrow = lane & 15;
    const int lk   = (lane >> 4) * 8;

    for (int kt = 0; kt < K; kt += TK) {
        const ushort* ga = A + (size_t)(row0 + wave * (TM / 4) + srow) * K + kt + scol;
        #pragma unroll
        for (int j = 0; j < FM; j++)
            gld_lds16(ga + (size_t)j * 8 * K, &As[wave * (TM / 4) + j * 8][0]);
        const ushort* gb = Bt + (size_t)(col0 + wave * (TN / 4) + srow) * K + kt + scol;
        #pragma unroll
        for (int j = 0; j < NF; j++)
            gld_lds16(gb + (size_t)j * 8 * K, &Bs[wave * (TN / 4) + j * 8][0]);
        __syncthreads();

        #pragma unroll
        for (int kk = 0; kk < TK; kk += 32) {
            bf16x8 af[FM], bfr[NF];
            #pragma unroll
            for (int i = 0; i < FM; i++)
                af[i] = *(const bf16x8*)(&As[wm * (FM * 16) + i * 16 + lrow][kk + lk]);
            #pragma unroll
            for (int j = 0; j < NF; j++)
                bfr[j] = *(const bf16x8*)(&Bs[wn * (TN / 2) + j * 16 + lrow][kk + lk]);
            #pragma unroll
            for (int i = 0; i < FM; i++)
                #pragma unroll
                for (int j = 0; j < NF; j++)
                    acc[i][j] = __builtin_amdgcn_mfma_f32_16x16x32_bf16(
                        af[i], bfr[j], acc[i][j], 0, 0, 0);
        }
        __syncthreads();
    }

    // C/D layout: col = lane&15, row = (lane>>4)*4 + reg  [m89/m91 verified]
    const int ccol = lane & 15;
    const int crow = (lane >> 4) * 4;
    #pragma unroll
    for (int j = 0; j < NF; j++) {
        int gcol = col0 + wn * (TN / 2) + j * 16 + ccol;
        float bias = (gcol < 512) ? b0[gcol]
                   : (gcol < 1024) ? b1[gcol - 512] : b2[gcol - 1024];
        #pragma unroll
        for (int i = 0; i < FM; i++) {
            int grow = row0 + wm * (FM * 16) + i * 16 + crow;
            #pragma unroll
            for (int rg = 0; rg < 4; rg++) {
                float v = acc[i][j][rg] + bias;
                if (BF16OUT)
                    ((ushort*)Cv)[(size_t)(grow + rg) * N + gcol] = f2bf(v);
                else
                    ((float*)Cv)[(size_t)(grow + rg) * N + gcol] = v;
            }
        }
    }
}

// ---------------- tree attention: 16B/lane ballot-scan gather ----------------
// PCS (bf16) row layout per token w (1536): [p(512)|c(512)|s(512)], each h*64+d.
// One wave per row n. Lane L owns 8 consecutive elements at offset L*8 of each
// 512-segment: head h = L>>3, dims (L&7)*8..+7. Per edge: two dwordx4 loads
// (c,s segments), 8-FMA dot partial, shfl_xor(1,2,4) reduce within the 8-lane
// head group, one exp, 8 FMAs. Neighbor set {parent[n]} ∪ {m:parent[m]==n}
// minus duplicates, processed in fixed order -> bit-deterministic. No atomics.
// NOTE: alpha is PER-HEAD — s must be attention-averaged per element BEFORE
// mixing through Wo (the s@Wo pre-fold is invalid; round-7 post-mortem).
__global__ __launch_bounds__(256) void attn_gather_kernel(
    const ushort* __restrict__ PCS, const int* __restrict__ parent,
    ushort* __restrict__ attn) {
    int gtid = blockIdx.x * blockDim.x + threadIdx.x;
    int w    = gtid >> 6;        // token row 0..BS_-1
    int lane = gtid & 63;
    int bbase = ((w >> 11) << 11);
    int i  = w & (S_ - 1);
    int rp = bbase + parent[w];

    // p fragment: 8 consecutive bf16 at w*1536 + lane*8
    float pnf[8];
    {
        us8 p8 = *(const us8*)(PCS + (size_t)w * N1_ + lane * 8);
        #pragma unroll
        for (int j = 0; j < 8; j++) pnf[j] = bf2f(p8[j]);
    }

    float Z, av[8];
    // parent edge (always present in the mask)
    {
        const ushort* rm = PCS + (size_t)rp * N1_;
        us8 c8 = *(const us8*)(rm + 512  + lane * 8);
        us8 s8 = *(const us8*)(rm + 1024 + lane * 8);
        float t = 0.f;
        #pragma unroll
        for (int j = 0; j < 8; j++) t += pnf[j] * bf2f(c8[j]);
        t += __shfl_xor(t, 1); t += __shfl_xor(t, 2); t += __shfl_xor(t, 4);
        float e = __expf(t * 0.125f);          // 1/sqrt(D) = 1/8
        Z = e;
        #pragma unroll
        for (int j = 0; j < 8; j++) av[j] = e * bf2f(s8[j]);
    }

    // children: scan this batch's parent slice, 256 ints per step (int4/lane)
    for (int t0 = 0; t0 < S_; t0 += 256) {
        int4 pv = *(const int4*)(parent + bbase + t0 + lane * 4);
        int pc[4] = {pv.x, pv.y, pv.z, pv.w};
        #pragma unroll
        for (int jj = 0; jj < 4; jj++) {
            unsigned long long mask = __ballot(pc[jj] == i);
            while (mask) {
                int l = __ffsll(mask) - 1;
                mask &= mask - 1;
                int c = bbase + t0 + l * 4 + jj;
                if (c == rp) continue;         // mutual/self edge counted once
                const ushort* rc = PCS + (size_t)c * N1_;
                us8 c8 = *(const us8*)(rc + 512  + lane * 8);
                us8 s8 = *(const us8*)(rc + 1024 + lane * 8);
                float t = 0.f;
                #pragma unroll
                for (int j = 0; j < 8; j++) t += pnf[j] * bf2f(c8[j]);
                t += __shfl_xor(t, 1); t += __shfl_xor(t, 2); t += __shfl_xor(t, 4);
                float e = __expf(t * 0.125f);
                Z += e;
                #pragma unroll
                for (int j = 0; j < 8; j++) av[j] += e * bf2f(s8[j]);
            }
        }
    }

    float rz = 1.0f / Z;
    us8 o8;
    #pragma unroll
    for (int j = 0; j < 8; j++) o8[j] = f2bf(av[j] * rz);
    *(us8*)(attn + (size_t)w * E_ + lane * 8) = o8;
}

// ---------------- launch ----------------
extern "C" void kernel_launch(void* const* d_in, const int* in_sizes, int n_in,
                              void* d_out, int out_size, void* d_ws, size_t ws_size,
                              hipStream_t stream) {
    const float* x      = (const float*)d_in[0];
    const int*   parent = (const int*)  d_in[1];
    const float* Wp     = (const float*)d_in[2];
    const float* bp     = (const float*)d_in[3];
    const float* Wc     = (const float*)d_in[4];
    const float* bc     = (const float*)d_in[5];
    const float* Ws     = (const float*)d_in[6];
    const float* bs     = (const float*)d_in[7];
    const float* Wo     = (const float*)d_in[8];
    const float* bo     = (const float*)d_in[9];
    float* out = (float*)d_out;

    char* ws = (char*)d_ws;
    // workspace layout (bytes, 256-aligned); every byte read is written first
    ushort* x_bf    = (ushort*)(ws + 0);          //  4,194,304
    ushort* Wcat_t  = (ushort*)(ws + 4194304);    //  1,572,864
    ushort* Wo_t    = (ushort*)(ws + 5767168);    //    524,288
    ushort* PCS_bf  = (ushort*)(ws + 6291456);    // 12,582,912
    ushort* attn_bf = (ushort*)(ws + 18874368);   //  4,194,304  (end ~23.1 MB)

    // prep: convert x (2048 blocks) + transpose weights (256 blocks)
    prep_kernel<<<2304, 256, 0, stream>>>(x, x_bf, Wp, Wc, Ws, Wo, Wcat_t, Wo_t);

    // GEMM1: PCS(bf16) = x @ [Wp|Wc|Ws] + [bp|bc|bs]
    // 128x96 tile -> 16x32 = 512 blocks = exactly 2.0 blocks/CU
    gemm_mfma_kernel<128, 96, true>
        <<<dim3(N1_ / 96, BS_ / 128), 256, 0, stream>>>(
        x_bf, Wcat_t, bp, bc, bs, PCS_bf, N1_, K_);

    // tree attention: deterministic gather, 16B/lane loads, no atomics
    attn_gather_kernel<<<BS_ * 64 / 256, 256, 0, stream>>>(
        PCS_bf, parent, attn_bf);

    // GEMM2: out(fp32) = attn @ Wo + bo
    // 64x64 tile -> 8x64 = 512 blocks = 2.0 blocks/CU (was 256 = 1/CU)
    gemm_mfma_kernel<64, 64, false>
        <<<dim3(E_ / 64, BS_ / 64), 256, 0, stream>>>(
        attn_bf, Wo_t, bo, bo, bo, out, E_, K_);
}